// Round 6
// baseline (81.861 us; speedup 1.0000x reference)
//
#include <hip/hip_runtime.h>

typedef unsigned short u16;
typedef __attribute__((ext_vector_type(4))) float f32x4;
typedef __attribute__((ext_vector_type(8))) short short8;

#define D0 784
#define D1 128
#define D2 64
#define D3 10
#define KS0 25
#define KS1 4
#define KS2 2

// workspace byte offsets
#define WS_W0P 0        // 25*128*32 u16 = 204800 B
#define WS_W1P 204800   // 4*64*32 u16   = 16384 B
#define WS_W2P 221184   // 2*16*32 u16   = 2048 B
#define WS_B0  223232   // 128 f32
#define WS_B1  223744   // 64 f32
#define WS_B2  224000   // 16 f32

__device__ __forceinline__ u16 f2bf(float f) {
  union { float f; unsigned u; } v; v.f = f;
  unsigned u = v.u;
  return (u16)((u + 0x7fffu + ((u >> 16) & 1u)) >> 16);  // RNE f32->bf16
}

// plain pack: [ks][col][32] bf16 k-step tiles (B-frags read straight from L2)
__global__ void prep_kernel(const float* __restrict__ W0, const float* __restrict__ W1,
                            const float* __restrict__ W2, u16* __restrict__ w0p,
                            u16* __restrict__ w1p, u16* __restrict__ w2p,
                            float* __restrict__ b0, float* __restrict__ b1,
                            float* __restrict__ b2) {
  int idx = blockIdx.x * 256 + threadIdx.x;
  if (idx < 25 * 128 * 32) {  // W0: [785][128] -> [25][128][32] (k zero-padded)
    int ks = idx / 4096, rem = idx % 4096, c = rem >> 5, kk = rem & 31;
    int k = ks * 32 + kk;
    float v = (k < D0) ? W0[k * D1 + c] : 0.f;
    w0p[ks * 4096 + c * 32 + kk] = f2bf(v);
    return;
  }
  idx -= 25 * 128 * 32;
  if (idx < 4 * 64 * 32) {  // W1: [129][64] -> [4][64][32]
    int ks = idx / 2048, rem = idx % 2048, c = rem >> 5, kk = rem & 31;
    int k = ks * 32 + kk;
    w1p[ks * 2048 + c * 32 + kk] = f2bf(W1[k * D2 + c]);
    return;
  }
  idx -= 4 * 64 * 32;
  if (idx < 2 * 16 * 32) {  // W2: [65][10] -> [2][16][32] (cols padded to 16)
    int ks = idx / 512, rem = idx % 512, c = rem >> 5, kk = rem & 31;
    int k = ks * 32 + kk;
    float v = (c < D3) ? W2[k * D3 + c] : 0.f;
    w2p[ks * 512 + c * 32 + kk] = f2bf(v);
    return;
  }
  idx -= 2 * 16 * 32;
  if (idx < 128) { b0[idx] = W0[D0 * D1 + idx]; return; }
  idx -= 128;
  if (idx < 64) { b1[idx] = W1[D1 * D2 + idx]; return; }
  idx -= 64;
  if (idx < 16) { b2[idx] = (idx < D3) ? W2[D2 * D3 + idx] : 0.f; }
}

__device__ __forceinline__ void cvtpk(unsigned& d, float lo, float hi) {
  asm("v_cvt_pk_bf16_f32 %0, %1, %2" : "=v"(d) : "v"(lo), "v"(hi));
}

// Barrier-free fused MLP: every wave fully independent through all 3 layers.
// 16 rows/wave, B-frags read directly from L2-resident packed weights, no
// manual waitcnt anywhere (compiler-managed per-register waits), LDS only as
// per-wave h0/h1 transpose scratch. 12 waves/CU via __launch_bounds__(256,3).
__global__ __launch_bounds__(256, 3) void mlp_fused(
    const float* __restrict__ X, const u16* __restrict__ w0p,
    const u16* __restrict__ w1p, const u16* __restrict__ w2p,
    const float* __restrict__ b0, const float* __restrict__ b1,
    const float* __restrict__ b2, float* __restrict__ out) {
  __shared__ __attribute__((aligned(16))) u16 smH[4][2048];  // 4 KB per wave

  const int t = threadIdx.x;
  const int lane = t & 63;
  const int wv = t >> 6;
  const int q = lane >> 4;    // k-chunk (A/B) / row-group (C)
  const int lr = lane & 15;   // A row / B,C col within fragment

  const int rowbase = blockIdx.x * 64 + wv * 16;
  const float* xrow = X + (size_t)(rowbase + lr) * D0;
  const u16* bp0 = w0p + lr * 32 + q * 8;   // + ks*4096 + f*512

  f32x4 acc[8];
#pragma unroll
  for (int f = 0; f < 8; ++f) acc[f] = (f32x4){0.f, 0.f, 0.f, 0.f};

  // main k-steps 0..23: all 32 k's in range (23*32+31 = 767 < 784)
#pragma unroll
  for (int ks = 0; ks < KS0 - 1; ++ks) {
    const f32x4* xp = (const f32x4*)(xrow + ks * 32 + q * 8);
    f32x4 xa = xp[0], xb = xp[1];
    short8 b[8];
#pragma unroll
    for (int f = 0; f < 8; ++f)
      b[f] = *(const short8*)(bp0 + ks * 4096 + f * 512);
    union { short8 s; unsigned u[4]; } a;
    cvtpk(a.u[0], xa[0], xa[1]); cvtpk(a.u[1], xa[2], xa[3]);
    cvtpk(a.u[2], xb[0], xb[1]); cvtpk(a.u[3], xb[2], xb[3]);
#pragma unroll
    for (int f = 0; f < 8; ++f)
      acc[f] = __builtin_amdgcn_mfma_f32_16x16x32_bf16(a.s, b[f], acc[f], 0, 0, 0);
  }
  // tail k-step 24: k = 768..799, only 768..783 valid. Lanes q>=2 would read
  // past the row (and past X for the final row) -> zero A-frags; exact
  // because W0p rows k>=784 are zero-padded.
  {
    const int ks = KS0 - 1;
    f32x4 xa = (f32x4){0.f, 0.f, 0.f, 0.f}, xb = xa;
    if (q < 2) {
      const f32x4* xp = (const f32x4*)(xrow + ks * 32 + q * 8);
      xa = xp[0]; xb = xp[1];
    }
    short8 b[8];
#pragma unroll
    for (int f = 0; f < 8; ++f)
      b[f] = *(const short8*)(bp0 + ks * 4096 + f * 512);
    union { short8 s; unsigned u[4]; } a;
    cvtpk(a.u[0], xa[0], xa[1]); cvtpk(a.u[1], xa[2], xa[3]);
    cvtpk(a.u[2], xb[0], xb[1]); cvtpk(a.u[3], xb[2], xb[3]);
#pragma unroll
    for (int f = 0; f < 8; ++f)
      acc[f] = __builtin_amdgcn_mfma_f32_16x16x32_bf16(a.s, b[f], acc[f], 0, 0, 0);
  }

  // ---- layer-0 epilogue: bias+relu -> swizzled per-wave h0[16][128] bf16 ----
  // byte(r,c) = r*256 + ((c>>3 ^ (r&7))<<4) + (c&7)*2
  char* hbase = (char*)&smH[wv][0];
#pragma unroll
  for (int f = 0; f < 8; ++f) {
    int c = f * 16 + lr;
    float bb = b0[c];
    int chb = (c >> 3) << 4;
    int cwb = (c & 7) << 1;
#pragma unroll
    for (int r = 0; r < 4; ++r) {
      int rr = q * 4 + r;
      *(u16*)(hbase + rr * 256 + (chb ^ ((rr & 7) << 4)) + cwb) =
          f2bf(fmaxf(acc[f][r] + bb, 0.f));
    }
  }
  __builtin_amdgcn_wave_barrier();

  // ---- layer 1: [16x128] @ [128x64], B-frags straight from L2 ----
  f32x4 acc1[4];
#pragma unroll
  for (int f = 0; f < 4; ++f) acc1[f] = (f32x4){0.f, 0.f, 0.f, 0.f};
  const u16* bp1 = w1p + lr * 32 + q * 8;
#pragma unroll
  for (int ks = 0; ks < KS1; ++ks) {
    short8 a = *(const short8*)(hbase + lr * 256 + (((ks * 4 + q) ^ (lr & 7)) << 4));
    short8 b[4];
#pragma unroll
    for (int f = 0; f < 4; ++f)
      b[f] = *(const short8*)(bp1 + ks * 2048 + f * 512);
#pragma unroll
    for (int f = 0; f < 4; ++f)
      acc1[f] = __builtin_amdgcn_mfma_f32_16x16x32_bf16(a, b[f], acc1[f], 0, 0, 0);
  }
  // layer-1 epilogue -> swizzled h1[16][64] (2 KB/wave, overlays dead h0)
  // byte(r,c) = r*128 + ((c>>3 ^ (r&7))<<4) + (c&7)*2
#pragma unroll
  for (int f = 0; f < 4; ++f) {
    int c = f * 16 + lr;
    float bb = b1[c];
    int chb = (c >> 3) << 4;
    int cwb = (c & 7) << 1;
#pragma unroll
    for (int r = 0; r < 4; ++r) {
      int rr = q * 4 + r;
      *(u16*)(hbase + rr * 128 + (chb ^ ((rr & 7) << 4)) + cwb) =
          f2bf(fmaxf(acc1[f][r] + bb, 0.f));
    }
  }
  __builtin_amdgcn_wave_barrier();

  // ---- layer 2: [16x64] @ [64x16(10 valid)] ----
  f32x4 acc2 = (f32x4){0.f, 0.f, 0.f, 0.f};
  const u16* bp2 = w2p + lr * 32 + q * 8;
#pragma unroll
  for (int ks = 0; ks < KS2; ++ks) {
    short8 a = *(const short8*)(hbase + lr * 128 + (((ks * 4 + q) ^ (lr & 7)) << 4));
    short8 b = *(const short8*)(bp2 + ks * 512);
    acc2 = __builtin_amdgcn_mfma_f32_16x16x32_bf16(a, b, acc2, 0, 0, 0);
  }
  if (lr < D3) {
    float bb = b2[lr];
#pragma unroll
    for (int r = 0; r < 4; ++r) {
      int rowg = rowbase + q * 4 + r;
      out[rowg * D3 + lr] = acc2[r] + bb;
    }
  }
}

extern "C" void kernel_launch(void* const* d_in, const int* in_sizes, int n_in,
                              void* d_out, int out_size, void* d_ws, size_t ws_size,
                              hipStream_t stream) {
  const float* X  = (const float*)d_in[0];
  const float* W0 = (const float*)d_in[1];
  const float* W1 = (const float*)d_in[2];
  const float* W2 = (const float*)d_in[3];
  float* out = (float*)d_out;
  char* ws = (char*)d_ws;
  u16* w0p = (u16*)(ws + WS_W0P);
  u16* w1p = (u16*)(ws + WS_W1P);
  u16* w2p = (u16*)(ws + WS_W2P);
  float* b0 = (float*)(ws + WS_B0);
  float* b1 = (float*)(ws + WS_B1);
  float* b2 = (float*)(ws + WS_B2);

  prep_kernel<<<437, 256, 0, stream>>>(W0, W1, W2, w0p, w1p, w2p, b0, b1, b2);
  mlp_fused<<<65536 / 64, 256, 0, stream>>>(X, w0p, w1p, w2p, b0, b1, b2, out);
}

// Round 8
// 49.759 us; speedup vs baseline: 1.6452x; 1.6452x over previous
//
#include <hip/hip_runtime.h>

typedef unsigned short u16;
typedef __attribute__((ext_vector_type(4))) float f32x4;
typedef __attribute__((ext_vector_type(8))) short short8;

#define D0 784
#define D1 128
#define D2 64
#define D3 10
#define KS0 25
#define KS1 4
#define KS2 2

// workspace byte offsets
#define WS_W0P 0        // 25*4096 u16 = 204800 B (swizzled tiles)
#define WS_W1P 204800   // 4*64*32 u16 = 16384 B (plain)
#define WS_W2P 221184   // 2*16*32 u16 = 2048 B  (plain)
#define WS_B0  223232   // 128 f32
#define WS_B1  223744   // 64 f32
#define WS_B2  224000   // 16 f32

__device__ __forceinline__ u16 f2bf(float f) {
  union { float f; unsigned u; } v; v.f = f;
  unsigned u = v.u;
  return (u16)((u + 0x7fffu + ((u >> 16) & 1u)) >> 16);  // RNE f32->bf16
}

// element offset of (col c, k-in-tile kk) inside a [C][32] bf16 k-step tile,
// with 16B-chunk XOR swizzle so ds_read_b128 of B-fragments is conflict-free.
__device__ __forceinline__ int swz(int c, int kk) {
  return c * 32 + (((kk >> 3) ^ ((c >> 1) & 3)) << 3) + (kk & 7);
}

__global__ void prep_kernel(const float* __restrict__ W0, const float* __restrict__ W1,
                            const float* __restrict__ W2, u16* __restrict__ w0p,
                            u16* __restrict__ w1p, u16* __restrict__ w2p,
                            float* __restrict__ b0, float* __restrict__ b1,
                            float* __restrict__ b2) {
  int idx = blockIdx.x * 256 + threadIdx.x;
  if (idx < KS0 * 4096) {  // W0: [785][128] -> [25][128][32] swizzled, k zero-padded
    int ks = idx / 4096, rem = idx % 4096, c = rem >> 5, kk = rem & 31;
    int k = ks * 32 + kk;
    float v = (k < D0) ? W0[k * D1 + c] : 0.f;
    w0p[ks * 4096 + swz(c, kk)] = f2bf(v);
    return;
  }
  idx -= KS0 * 4096;
  if (idx < 4 * 64 * 32) {  // W1: [129][64] -> [4][64][32] plain (L2-direct reads)
    int ks = idx / 2048, rem = idx % 2048, c = rem >> 5, kk = rem & 31;
    int k = ks * 32 + kk;
    w1p[ks * 2048 + c * 32 + kk] = f2bf(W1[k * D2 + c]);
    return;
  }
  idx -= 4 * 64 * 32;
  if (idx < 2 * 16 * 32) {  // W2: [65][10] -> [2][16][32] plain (cols padded to 16)
    int ks = idx / 512, rem = idx % 512, c = rem >> 5, kk = rem & 31;
    int k = ks * 32 + kk;
    float v = (c < D3) ? W2[k * D3 + c] : 0.f;
    w2p[ks * 512 + c * 32 + kk] = f2bf(v);
    return;
  }
  idx -= 2 * 16 * 32;
  if (idx < 128) { b0[idx] = W0[D0 * D1 + idx]; return; }
  idx -= 128;
  if (idx < 64) { b1[idx] = W1[D1 * D2 + idx]; return; }
  idx -= 64;
  if (idx < 16) { b2[idx] = (idx < D3) ? W2[D2 * D3 + idx] : 0.f; }
}

__device__ __forceinline__ void gload_lds16(const void* g, void* l) {
  __builtin_amdgcn_global_load_lds((const __attribute__((address_space(1))) void*)g,
                                   (__attribute__((address_space(3))) void*)l, 16, 0, 0);
}

__device__ __forceinline__ void cvtpk(unsigned& d, float lo, float hi) {
  asm("v_cvt_pk_bf16_f32 %0, %1, %2" : "=v"(d) : "v"(lo), "v"(hi));
}

// Fused MLP, round-2 backbone re-tiled to 2-wave blocks for barrier decoupling:
// 32 rows/block, 2048 blocks -> 8 independent barrier domains per CU.
// W0 double-buffered in LDS (proven k-loop); W1/W2/biases L2-direct (proven);
// h0/h1 overlay the W0 buffers after the final barrier (proven).
__global__ __launch_bounds__(128, 4) void mlp_fused(
    const float* __restrict__ X, const u16* __restrict__ w0p,
    const u16* __restrict__ w1p, const u16* __restrict__ w2p,
    const float* __restrict__ b0, const float* __restrict__ b1,
    const float* __restrict__ b2, float* __restrict__ out) {
  __shared__ __attribute__((aligned(16))) u16 smW0[2][4096];  // 2 x 8 KB tiles

  const int t = threadIdx.x;
  const int lane = t & 63;
  const int wv = t >> 6;      // 0..1
  const int q = lane >> 4;    // k-chunk (A/B) / row-group (C)
  const int lr = lane & 15;   // A row / B,C col within fragment

  const int rowbase = blockIdx.x * 32 + wv * 16;
  const float* xrow = X + (size_t)(rowbase + lr) * D0;

  // W0 tile staging: each of 2 waves copies 4 KB of the 8 KB tile (4 x 1 KB)
  auto stageW0 = [&](int buf, int ks) {
    const char* src = (const char*)(w0p + ks * 4096) + wv * 4096 + lane * 16;
    char* dst = (char*)&smW0[buf][0] + wv * 4096;
    gload_lds16(src, dst);
    gload_lds16(src + 1024, dst + 1024);
    gload_lds16(src + 2048, dst + 2048);
    gload_lds16(src + 3072, dst + 3072);
  };

  f32x4 acc[8];
#pragma unroll
  for (int f = 0; f < 8; ++f) acc[f] = (f32x4){0.f, 0.f, 0.f, 0.f};

  // prologue: X(0) then stage(0)
  f32x4 xa, xb;
  {
    const f32x4* xp = (const f32x4*)(xrow + q * 8);
    xa = xp[0]; xb = xp[1];
  }
  stageW0(0, 0);
  __syncthreads();

  // per-lane constant part of the B-fragment LDS offset (u16 elements)
  const int boff = lr * 32 + (q ^ ((lr >> 1) & 3)) * 8;

  int buf = 0;
  for (int ks = 0; ks < KS0; ++ks) {
    // issue next-tile X first (HBM, longest latency), then stage (L2)
    f32x4 na = (f32x4){0.f, 0.f, 0.f, 0.f}, nb = (f32x4){0.f, 0.f, 0.f, 0.f};
    if (ks + 1 < KS0) {
      int kb = (ks + 1) * 32 + q * 8;
      if (kb < D0) {  // k-tail (>=784) contributes 0 anyway (W0p zero-padded)
        const f32x4* xp = (const f32x4*)(xrow + kb);
        na = xp[0]; nb = xp[1];
      }
      stageW0(buf ^ 1, ks + 1);
    }
    union { short8 s; unsigned u[4]; } a;
    cvtpk(a.u[0], xa[0], xa[1]);
    cvtpk(a.u[1], xa[2], xa[3]);
    cvtpk(a.u[2], xb[0], xb[1]);
    cvtpk(a.u[3], xb[2], xb[3]);
    const u16* smb = &smW0[buf][0];
#pragma unroll
    for (int f = 0; f < 8; ++f) {
      short8 b = *(const short8*)(smb + f * 512 + boff);
      acc[f] = __builtin_amdgcn_mfma_f32_16x16x32_bf16(a.s, b, acc[f], 0, 0, 0);
    }
    __syncthreads();
    xa = na; xb = nb; buf ^= 1;
  }

  // ---- per-wave scratch region (overlays smW0, safe after final barrier) ----
  char* hbase = (char*)&smW0[0][0] + wv * 4096;

  // layer-0 epilogue: bias + relu -> swizzled h0[16][128] bf16 (4 KB/wave)
  // byte(r,c) = r*256 + ((c>>3 ^ (r&7))<<4) + (c&7)*2
#pragma unroll
  for (int f = 0; f < 8; ++f) {
    int c = f * 16 + lr;
    float bb = b0[c];
    int chb = (c >> 3) << 4;
    int cwb = (c & 7) << 1;
#pragma unroll
    for (int r = 0; r < 4; ++r) {
      int rr = q * 4 + r;
      *(u16*)(hbase + rr * 256 + (chb ^ ((rr & 7) << 4)) + cwb) =
          f2bf(fmaxf(acc[f][r] + bb, 0.f));
    }
  }
  __builtin_amdgcn_wave_barrier();  // per-wave data; no cross-wave sync needed

  // ---- layer 1: [16x128] @ [128x64], B-frags straight from L2 ----
  f32x4 acc1[4];
#pragma unroll
  for (int f = 0; f < 4; ++f) acc1[f] = (f32x4){0.f, 0.f, 0.f, 0.f};
  const u16* bp1 = w1p + lr * 32 + q * 8;
#pragma unroll
  for (int ks = 0; ks < KS1; ++ks) {
    short8 a = *(const short8*)(hbase + lr * 256 + (((ks * 4 + q) ^ (lr & 7)) << 4));
    short8 b[4];
#pragma unroll
    for (int f = 0; f < 4; ++f)
      b[f] = *(const short8*)(bp1 + ks * 2048 + f * 512);
#pragma unroll
    for (int f = 0; f < 4; ++f)
      acc1[f] = __builtin_amdgcn_mfma_f32_16x16x32_bf16(a, b[f], acc1[f], 0, 0, 0);
  }
  // layer-1 epilogue -> swizzled h1[16][64] (2 KB/wave, overlays dead h0)
  // byte(r,c) = r*128 + ((c>>3 ^ (r&7))<<4) + (c&7)*2
#pragma unroll
  for (int f = 0; f < 4; ++f) {
    int c = f * 16 + lr;
    float bb = b1[c];
    int chb = (c >> 3) << 4;
    int cwb = (c & 7) << 1;
#pragma unroll
    for (int r = 0; r < 4; ++r) {
      int rr = q * 4 + r;
      *(u16*)(hbase + rr * 128 + (chb ^ ((rr & 7) << 4)) + cwb) =
          f2bf(fmaxf(acc1[f][r] + bb, 0.f));
    }
  }
  __builtin_amdgcn_wave_barrier();

  // ---- layer 2: [16x64] @ [64x16(10 valid)] ----
  f32x4 acc2 = (f32x4){0.f, 0.f, 0.f, 0.f};
  const u16* bp2 = w2p + lr * 32 + q * 8;
#pragma unroll
  for (int ks = 0; ks < KS2; ++ks) {
    short8 a = *(const short8*)(hbase + lr * 128 + (((ks * 4 + q) ^ (lr & 7)) << 4));
    short8 b = *(const short8*)(bp2 + ks * 512);
    acc2 = __builtin_amdgcn_mfma_f32_16x16x32_bf16(a, b, acc2, 0, 0, 0);
  }
  if (lr < D3) {
    float bb = b2[lr];
#pragma unroll
    for (int r = 0; r < 4; ++r) {
      int rowg = rowbase + q * 4 + r;
      out[rowg * D3 + lr] = acc2[r] + bb;
    }
  }
}

extern "C" void kernel_launch(void* const* d_in, const int* in_sizes, int n_in,
                              void* d_out, int out_size, void* d_ws, size_t ws_size,
                              hipStream_t stream) {
  const float* X  = (const float*)d_in[0];
  const float* W0 = (const float*)d_in[1];
  const float* W1 = (const float*)d_in[2];
  const float* W2 = (const float*)d_in[3];
  float* out = (float*)d_out;
  char* ws = (char*)d_ws;
  u16* w0p = (u16*)(ws + WS_W0P);
  u16* w1p = (u16*)(ws + WS_W1P);
  u16* w2p = (u16*)(ws + WS_W2P);
  float* b0 = (float*)(ws + WS_B0);
  float* b1 = (float*)(ws + WS_B1);
  float* b2 = (float*)(ws + WS_B2);

  // total prep elements: 102400 + 8192 + 1024 + 128 + 64 + 16 = 111824
  prep_kernel<<<437, 256, 0, stream>>>(W0, W1, W2, w0p, w1p, w2p, b0, b1, b2);
  mlp_fused<<<65536 / 32, 128, 0, stream>>>(X, w0p, w1p, w2p, b0, b1, b2, out);
}

// Round 9
// 46.318 us; speedup vs baseline: 1.7673x; 1.0743x over previous
//
#include <hip/hip_runtime.h>

typedef unsigned short u16;
typedef __attribute__((ext_vector_type(4))) float f32x4;
typedef __attribute__((ext_vector_type(8))) short short8;

#define D0 784
#define D1 128
#define D2 64
#define D3 10
#define KS0 25
#define KS1 4
#define KS2 2

// workspace byte offsets
#define WS_W0P 0        // 25*128*32 u16 = 204800 B (swizzled tiles)
#define WS_W1P 204800   // 4*64*32 u16   = 16384 B  (swizzled, W2P contiguous)
#define WS_W2P 221184   // 2*16*32 u16   = 2048 B   (swizzled)
#define WS_B0  223232   // 128 f32
#define WS_B1  223744   // 64 f32
#define WS_B2  224000   // 16 f32

__device__ __forceinline__ u16 f2bf(float f) {
  union { float f; unsigned u; } v; v.f = f;
  unsigned u = v.u;
  return (u16)((u + 0x7fffu + ((u >> 16) & 1u)) >> 16);  // RNE f32->bf16
}

// element offset of (col c, k-in-tile kk) inside a [C][32] bf16 k-step tile,
// with 16B-chunk XOR swizzle so ds_read_b128 of B-fragments is conflict-free.
__device__ __forceinline__ int swz(int c, int kk) {
  return c * 32 + (((kk >> 3) ^ ((c >> 1) & 3)) << 3) + (kk & 7);
}

// Coalesced-read prep: thread idx maps to (k, c) with c fastest -> linear
// reads of W0/W1; scattered swizzled writes (stores don't stall the wave).
__global__ void prep_kernel(const float* __restrict__ W0, const float* __restrict__ W1,
                            const float* __restrict__ W2, u16* __restrict__ w0p,
                            u16* __restrict__ w1p, u16* __restrict__ w2p,
                            float* __restrict__ b0, float* __restrict__ b1,
                            float* __restrict__ b2) {
  int idx = blockIdx.x * 256 + threadIdx.x;
  if (idx < 800 * 128) {  // W0: [785][128] -> [25][128][32] swizzled, k zero-padded
    int k = idx >> 7, c = idx & 127;
    float v = (k < D0) ? W0[idx] : 0.f;  // idx == k*128 + c; k>=784 zero (incl bias row)
    w0p[(k >> 5) * 4096 + swz(c, k & 31)] = f2bf(v);
    return;
  }
  idx -= 800 * 128;
  if (idx < 128 * 64) {  // W1: rows 0..127 -> [4][64][32] swizzled
    int k = idx >> 6, c = idx & 63;
    w1p[(k >> 5) * 2048 + swz(c, k & 31)] = f2bf(W1[idx]);
    return;
  }
  idx -= 128 * 64;
  if (idx < 64 * 16) {  // W2: rows 0..63 -> [2][16][32] swizzled (cols padded to 16)
    int k = idx >> 4, c = idx & 15;
    float v = (c < D3) ? W2[k * D3 + c] : 0.f;
    w2p[(k >> 5) * 512 + swz(c, k & 31)] = f2bf(v);
    return;
  }
  idx -= 64 * 16;
  if (idx < 128) { b0[idx] = W0[D0 * D1 + idx]; return; }
  idx -= 128;
  if (idx < 64) { b1[idx] = W1[D1 * D2 + idx]; return; }
  idx -= 64;
  if (idx < 16) { b2[idx] = (idx < D3) ? W2[D2 * D3 + idx] : 0.f; }
}

__device__ __forceinline__ void gload_lds16(const void* g, void* l) {
  __builtin_amdgcn_global_load_lds((const __attribute__((address_space(1))) void*)g,
                                   (__attribute__((address_space(3))) void*)l, 16, 0, 0);
}

__device__ __forceinline__ void cvtpk(unsigned& d, float lo, float hi) {
  asm("v_cvt_pk_bf16_f32 %0, %1, %2" : "=v"(d) : "v"(lo), "v"(hi));
}

// R2 backbone with same-iteration X consumption: X(ks) loaded at top of iter
// ks -> compiler's precise vmcnt wait lands mid-iteration (per-wave,
// uncorrelated, hidden by 16 waves/CU); at the barrier only the L2 stage is
// in flight, so the vmcnt(0) drain is cheap. Loop kept rolled so the
// scheduler cannot hoist X loads back across the barrier.
__global__ __launch_bounds__(256, 4) void mlp_fused(
    const float* __restrict__ X, const u16* __restrict__ w0p,
    const u16* __restrict__ w1p, const float* __restrict__ b0,
    const float* __restrict__ b1, const float* __restrict__ b2,
    float* __restrict__ out) {
  // smW0 double-buffer (16 KB); reused per-wave for h0/h1 after the k-loop.
  __shared__ __attribute__((aligned(16))) u16 smW0[2][4096];
  __shared__ __attribute__((aligned(16))) u16 smW12[9216];  // W1p (16 KB) + W2p (2 KB)

  const int t = threadIdx.x;
  const int lane = t & 63;
  const int wv = t >> 6;
  const int q = lane >> 4;    // k-chunk (A/B) / row-group (C)
  const int lr = lane & 15;   // A row / B,C col within fragment

  // stage W1p + W2p (contiguous 18432 B in ws) into LDS
  {
    const char* src = (const char*)w1p;
    char* dst = (char*)smW12;
    for (int off = wv * 1024; off < 18432; off += 4096)
      gload_lds16(src + off + lane * 16, dst + off);
  }
  // W0 k-tile staging: each wave copies 2 KB (2 x 1 KB instructions)
  auto stageW0 = [&](int buf, int ks) {
    const char* src = (const char*)(w0p + ks * 4096) + wv * 2048 + lane * 16;
    char* dst = (char*)&smW0[buf][0] + wv * 2048;
    gload_lds16(src, dst);
    gload_lds16(src + 1024, dst + 1024);
  };

  const int rowbase = blockIdx.x * 64 + wv * 16;
  const float* xrow = X + (size_t)(rowbase + lr) * D0;

  f32x4 acc[8];
#pragma unroll
  for (int f = 0; f < 8; ++f) acc[f] = (f32x4){0.f, 0.f, 0.f, 0.f};

  stageW0(0, 0);
  __syncthreads();

  // per-lane constant part of the B-fragment LDS offset (u16 elements)
  const int boff = lr * 32 + (q ^ ((lr >> 1) & 3)) * 8;

  int buf = 0;
#pragma clang loop unroll(disable)
  for (int ks = 0; ks < KS0; ++ks) {
    // this iteration's X first (HBM; retired mid-iteration at cvtpk)
    f32x4 xa = (f32x4){0.f, 0.f, 0.f, 0.f}, xb = xa;
    int kb = ks * 32 + q * 8;
    if (kb < D0) {  // divergent only at ks=24; zero A x zero-padded B is exact
      const f32x4* xp = (const f32x4*)(xrow + kb);
      xa = xp[0]; xb = xp[1];
    }
    // next tile stage (L2 -> LDS DMA; drained at this iteration's barrier)
    if (ks + 1 < KS0) stageW0(buf ^ 1, ks + 1);
    union { short8 s; unsigned u[4]; } a;
    cvtpk(a.u[0], xa[0], xa[1]);
    cvtpk(a.u[1], xa[2], xa[3]);
    cvtpk(a.u[2], xb[0], xb[1]);
    cvtpk(a.u[3], xb[2], xb[3]);
    const u16* smb = &smW0[buf][0];
#pragma unroll
    for (int f = 0; f < 8; ++f) {
      short8 b = *(const short8*)(smb + f * 512 + boff);
      acc[f] = __builtin_amdgcn_mfma_f32_16x16x32_bf16(a.s, b, acc[f], 0, 0, 0);
    }
    __syncthreads();
    buf ^= 1;
  }

  // ---- per-wave scratch region (overlays smW0, safe after final barrier) ----
  char* hbase = (char*)&smW0[0][0] + wv * 4096;

  // layer-0 epilogue: bias + relu -> swizzled h0[16][128] bf16 (4 KB/wave)
  // byte(r,c) = r*256 + ((c>>3 ^ (r&7))<<4) + (c&7)*2
#pragma unroll
  for (int f = 0; f < 8; ++f) {
    int c = f * 16 + lr;
    float bb = b0[c];
    int chb = ((c >> 3) << 4);
    int cwb = (c & 7) << 1;
#pragma unroll
    for (int r = 0; r < 4; ++r) {
      int rr = q * 4 + r;
      float v = acc[f][r] + bb;
      *(u16*)(hbase + rr * 256 + (chb ^ ((rr & 7) << 4)) + cwb) = f2bf(fmaxf(v, 0.f));
    }
  }
  __builtin_amdgcn_wave_barrier();  // per-wave data; no cross-wave sync needed

  // layer 1: [16x128] @ [128x64], A-frags from swizzled h0, B from LDS
  f32x4 acc1[4];
#pragma unroll
  for (int f = 0; f < 4; ++f) acc1[f] = (f32x4){0.f, 0.f, 0.f, 0.f};
#pragma unroll
  for (int ks = 0; ks < KS1; ++ks) {
    short8 a = *(const short8*)(hbase + lr * 256 + (((ks * 4 + q) ^ (lr & 7)) << 4));
#pragma unroll
    for (int f = 0; f < 4; ++f) {
      int c = f * 16 + lr;
      int js = q ^ ((c >> 1) & 3);
      short8 b = *(const short8*)(smW12 + ks * 2048 + c * 32 + js * 8);
      acc1[f] = __builtin_amdgcn_mfma_f32_16x16x32_bf16(a, b, acc1[f], 0, 0, 0);
    }
  }
  // layer-1 epilogue -> swizzled h1[16][64] bf16 (2 KB/wave, overlays dead h0)
  // byte(r,c) = r*128 + ((c>>3 ^ (r&7))<<4) + (c&7)*2
#pragma unroll
  for (int f = 0; f < 4; ++f) {
    int c = f * 16 + lr;
    float bb = b1[c];
    int chb = ((c >> 3) << 4);
    int cwb = (c & 7) << 1;
#pragma unroll
    for (int r = 0; r < 4; ++r) {
      int rr = q * 4 + r;
      *(u16*)(hbase + rr * 128 + (chb ^ ((rr & 7) << 4)) + cwb) =
          f2bf(fmaxf(acc1[f][r] + bb, 0.f));
    }
  }
  __builtin_amdgcn_wave_barrier();

  // layer 2: [16x64] @ [64x16(10 valid)]
  f32x4 acc2 = (f32x4){0.f, 0.f, 0.f, 0.f};
  const u16* w2sm = smW12 + 8192;
#pragma unroll
  for (int ks = 0; ks < KS2; ++ks) {
    short8 a = *(const short8*)(hbase + lr * 128 + (((ks * 4 + q) ^ (lr & 7)) << 4));
    int js = q ^ ((lr >> 1) & 3);
    short8 b = *(const short8*)(w2sm + ks * 512 + lr * 32 + js * 8);
    acc2 = __builtin_amdgcn_mfma_f32_16x16x32_bf16(a, b, acc2, 0, 0, 0);
  }
  if (lr < D3) {
    float bb = b2[lr];
#pragma unroll
    for (int r = 0; r < 4; ++r) {
      int rowg = rowbase + q * 4 + r;
      out[rowg * D3 + lr] = acc2[r] + bb;
    }
  }
}

extern "C" void kernel_launch(void* const* d_in, const int* in_sizes, int n_in,
                              void* d_out, int out_size, void* d_ws, size_t ws_size,
                              hipStream_t stream) {
  const float* X  = (const float*)d_in[0];
  const float* W0 = (const float*)d_in[1];
  const float* W1 = (const float*)d_in[2];
  const float* W2 = (const float*)d_in[3];
  float* out = (float*)d_out;
  char* ws = (char*)d_ws;
  u16* w0p = (u16*)(ws + WS_W0P);
  u16* w1p = (u16*)(ws + WS_W1P);
  u16* w2p = (u16*)(ws + WS_W2P);
  float* b0 = (float*)(ws + WS_B0);
  float* b1 = (float*)(ws + WS_B1);
  float* b2 = (float*)(ws + WS_B2);

  // total prep elements: 102400 + 8192 + 1024 + 128 + 64 + 16 = 111824
  prep_kernel<<<437, 256, 0, stream>>>(W0, W1, W2, w0p, w1p, w2p, b0, b1, b2);
  mlp_fused<<<65536 / 64, 256, 0, stream>>>(X, w0p, w1p, b0, b1, b2, out);
}